// Round 9
// baseline (371.007 us; speedup 1.0000x reference)
//
#include <hip/hip_runtime.h>
#include <cstdint>

constexpr int BSHIFT = 9;               // 512 nodes per bucket
constexpr int NBUCK  = 256;             // max buckets (covers 131072 nodes)
constexpr int BUCKET_CAP = 6144;        // slot capacity; E/bucket ~ Poisson(5102), 14 sigma

__device__ __forceinline__ float4 add4(float4 a, float4 b) {
    return make_float4(a.x + b.x, a.y + b.y, a.z + b.z, a.w + b.w);
}
__device__ __forceinline__ float4 mul4s(float4 a, float s) {
    return make_float4(a.x * s, a.y * s, a.z * s, a.w * s);
}

// ---------------- CSR build (bucketed, LDS-local, packed pairs) ----------------

__global__ void zero_ints(int* __restrict__ p, int n) {
    int i = blockIdx.x * blockDim.x + threadIdx.x;
    if (i < n) p[i] = 0;
}

// pack: (src << 9) | localDst  (src < 2^17 -> fits positive int with 9-bit local)
constexpr int EPT = 16;  // edges per thread; chunk = 4096
__global__ __launch_bounds__(256) void partition_edges(
    const int* __restrict__ src, const int* __restrict__ dst,
    int* __restrict__ bucketCur, int* __restrict__ pairs, int ne) {
    __shared__ int lcnt[NBUCK];
    __shared__ int lbase[NBUCK];
    int base = blockIdx.x * (256 * EPT);
    if (threadIdx.x < NBUCK) lcnt[threadIdx.x] = 0;
    __syncthreads();
    int2 ed[EPT];
    int  rnk[EPT];
#pragma unroll
    for (int j = 0; j < EPT; ++j) {
        int e = base + j * 256 + threadIdx.x;
        if (e < ne) {
            int d = dst[e];
            ed[j] = make_int2(src[e], d);
            rnk[j] = atomicAdd(&lcnt[d >> BSHIFT], 1);
        } else {
            ed[j].y = -1;
        }
    }
    __syncthreads();
    if (threadIdx.x < NBUCK) {
        int c = lcnt[threadIdx.x];
        lbase[threadIdx.x] = c ? atomicAdd(&bucketCur[threadIdx.x], c) : 0;
    }
    __syncthreads();
#pragma unroll
    for (int j = 0; j < EPT; ++j) {
        if (ed[j].y >= 0) {
            int b = ed[j].y >> BSHIFT;
            int p = lbase[b] + rnk[j];
            if (p < BUCKET_CAP)  // never hit for this input; guards corruption
                pairs[(size_t)b * BUCKET_CAP + p] =
                    (ed[j].x << BSHIFT) | (ed[j].y & ((1 << BSHIFT) - 1));
        }
    }
}

__global__ void scan_buckets(const int* __restrict__ bucketCnt, int* __restrict__ bucketBase,
                             int* __restrict__ offs, int n, int ne, int nbuckets) {
    __shared__ int tmp[256];
    int c = (threadIdx.x < (unsigned)nbuckets) ? bucketCnt[threadIdx.x] : 0;
    tmp[threadIdx.x] = c;
    __syncthreads();
    for (int off = 1; off < 256; off <<= 1) {
        int t = (threadIdx.x >= (unsigned)off) ? tmp[threadIdx.x - off] : 0;
        __syncthreads();
        tmp[threadIdx.x] += t;
        __syncthreads();
    }
    if (threadIdx.x < (unsigned)nbuckets) bucketBase[threadIdx.x] = tmp[threadIdx.x] - c;
    if (threadIdx.x == 0) offs[n] = ne;
}

__global__ __launch_bounds__(256) void bucket_csr(
    const int* __restrict__ pairs, const int* __restrict__ bucketCnt,
    const int* __restrict__ bucketBase, int* __restrict__ offs,
    float* __restrict__ dinv, int* __restrict__ csr, int n) {
    constexpr int BN = 1 << BSHIFT;  // 512
    __shared__ int hist[BN];
    __shared__ int cur[BN];
    __shared__ int tmp[256];
    int b = blockIdx.x;
    int cnt  = bucketCnt[b];
    int base = bucketBase[b];
    const int* pb = pairs + (size_t)b * BUCKET_CAP;
    int nodeLo = b << BSHIFT;

    hist[threadIdx.x] = 0;
    hist[threadIdx.x + 256] = 0;
    __syncthreads();
    for (int e = threadIdx.x; e < cnt; e += 256)
        atomicAdd(&hist[pb[e] & (BN - 1)], 1);
    __syncthreads();

    int l0 = 2 * threadIdx.x, l1 = l0 + 1;
    int h0 = hist[l0], h1 = hist[l1];
    tmp[threadIdx.x] = h0 + h1;
    __syncthreads();
    for (int off = 1; off < 256; off <<= 1) {
        int t = (threadIdx.x >= (unsigned)off) ? tmp[threadIdx.x - off] : 0;
        __syncthreads();
        tmp[threadIdx.x] += t;
        __syncthreads();
    }
    int e0 = tmp[threadIdx.x] - (h0 + h1);
    int e1 = e0 + h0;
    int g0 = nodeLo + l0, g1 = nodeLo + l1;
    if (g0 < n) { offs[g0] = base + e0; dinv[g0] = rsqrtf((float)(h0 + 1)); }
    if (g1 < n) { offs[g1] = base + e1; dinv[g1] = rsqrtf((float)(h1 + 1)); }
    cur[l0] = e0;
    cur[l1] = e1;
    __syncthreads();

    for (int e = threadIdx.x; e < cnt; e += 256) {
        int p = pb[e];
        int pos = atomicAdd(&cur[p & (BN - 1)], 1);
        csr[base + pos] = ((unsigned)p) >> BSHIFT;
    }
}

// ---------------- fused layer-1: agg(K=64) + gemm(64->100,relu) + gemm(100->50,*dinv) ----
// Block = 32 nodes. Phase A: gather-aggregate into LDS Xs[k][node] (transposed).
// Phase B: H = relu(Xs@W1 + b1) -> LDS Hs (W1 from global, L1-resident).
// Phase C: out = (Hs@W2)*dinv -> bufA (stride 64, cols 0..49).
__global__ __launch_bounds__(256) void fused_l1(
    const float* __restrict__ x, const int* __restrict__ offs,
    const int* __restrict__ csr, const float* __restrict__ dinv,
    const float* __restrict__ W1, const float* __restrict__ b1,
    const float* __restrict__ W2, float* __restrict__ out, int n) {
    constexpr int NT = 32, NTp = 36;
    __shared__ float Xs[64 * NTp];    // 9.2 KB
    __shared__ float Hs[100 * NTp];   // 14.4 KB
    int blockBase = blockIdx.x * NT;

    // ---- phase A ----
    {
        int lane = threadIdx.x & 15;
        int f0 = lane * 4;
#pragma unroll
        for (int pass = 0; pass < 2; ++pass) {
            int nl = pass * 16 + (threadIdx.x >> 4);
            int node = blockBase + nl;
            float4 r = make_float4(0.f, 0.f, 0.f, 0.f);
            if (node < n) {
                float dv = dinv[node];
                float4 z = make_float4(0.f, 0.f, 0.f, 0.f);
                float4 acc0 = mul4s(*(const float4*)&x[(size_t)node * 64 + f0], dv);
                float4 acc1 = z, acc2 = z, acc3 = z;
                int e0 = offs[node], e1 = offs[node + 1];
                int e = e0;
                for (; e + 4 <= e1; e += 4) {
                    int i0 = csr[e], i1 = csr[e + 1], i2 = csr[e + 2], i3 = csr[e + 3];
                    float4 v0 = *(const float4*)&x[(size_t)i0 * 64 + f0];
                    float4 v1 = *(const float4*)&x[(size_t)i1 * 64 + f0];
                    float4 v2 = *(const float4*)&x[(size_t)i2 * 64 + f0];
                    float4 v3 = *(const float4*)&x[(size_t)i3 * 64 + f0];
                    v0 = mul4s(v0, dinv[i0]); v1 = mul4s(v1, dinv[i1]);
                    v2 = mul4s(v2, dinv[i2]); v3 = mul4s(v3, dinv[i3]);
                    acc0 = add4(acc0, v0); acc1 = add4(acc1, v1);
                    acc2 = add4(acc2, v2); acc3 = add4(acc3, v3);
                }
                for (; e < e1; ++e) {
                    int sid = csr[e];
                    acc0 = add4(acc0, mul4s(*(const float4*)&x[(size_t)sid * 64 + f0], dinv[sid]));
                }
                float4 acc = add4(add4(acc0, acc1), add4(acc2, acc3));
                r = mul4s(acc, dv);
            }
            Xs[(f0 + 0) * NTp + nl] = r.x;
            Xs[(f0 + 1) * NTp + nl] = r.y;
            Xs[(f0 + 2) * NTp + nl] = r.z;
            Xs[(f0 + 3) * NTp + nl] = r.w;
        }
    }
    __syncthreads();

    // ---- phase B: K=64, M=100, NTILES = 8*25 = 200 ----
    if (threadIdx.x < 200) {
        int ng = threadIdx.x / 25, mq = threadIdx.x % 25;
        int n0 = ng * 4, m0 = mq * 4;
        float acc[4][4] = {};
#pragma unroll 4
        for (int k = 0; k < 64; ++k) {
            float4 xv = *(const float4*)&Xs[k * NTp + n0];
            float4 wv = *(const float4*)&W1[k * 100 + m0];
            acc[0][0] = fmaf(xv.x, wv.x, acc[0][0]); acc[0][1] = fmaf(xv.x, wv.y, acc[0][1]);
            acc[0][2] = fmaf(xv.x, wv.z, acc[0][2]); acc[0][3] = fmaf(xv.x, wv.w, acc[0][3]);
            acc[1][0] = fmaf(xv.y, wv.x, acc[1][0]); acc[1][1] = fmaf(xv.y, wv.y, acc[1][1]);
            acc[1][2] = fmaf(xv.y, wv.z, acc[1][2]); acc[1][3] = fmaf(xv.y, wv.w, acc[1][3]);
            acc[2][0] = fmaf(xv.z, wv.x, acc[2][0]); acc[2][1] = fmaf(xv.z, wv.y, acc[2][1]);
            acc[2][2] = fmaf(xv.z, wv.z, acc[2][2]); acc[2][3] = fmaf(xv.z, wv.w, acc[2][3]);
            acc[3][0] = fmaf(xv.w, wv.x, acc[3][0]); acc[3][1] = fmaf(xv.w, wv.y, acc[3][1]);
            acc[3][2] = fmaf(xv.w, wv.z, acc[3][2]); acc[3][3] = fmaf(xv.w, wv.w, acc[3][3]);
        }
        float4 bb = *(const float4*)&b1[m0];
        float bv[4] = {bb.x, bb.y, bb.z, bb.w};
#pragma unroll
        for (int j = 0; j < 4; ++j)
#pragma unroll
            for (int i = 0; i < 4; ++i)
                Hs[(m0 + i) * NTp + n0 + j] = fmaxf(acc[j][i] + bv[i], 0.0f);
    }
    __syncthreads();

    // ---- phase C: K=100, M=50 (Mp=52, MQ=13), NTILES = 8*13 = 104 ----
    if (threadIdx.x < 104) {
        int ng = threadIdx.x / 13, mq = threadIdx.x % 13;
        int n0 = ng * 4, m0 = mq * 4;
        bool full = (m0 + 3 < 50);
        float acc[4][4] = {};
#pragma unroll 2
        for (int k = 0; k < 100; ++k) {
            float4 xv = *(const float4*)&Hs[k * NTp + n0];
            float4 wv;
            if (full) {   // W2 rows stride 50 floats: 8B-aligned -> float2 pairs
                float2 wa = *(const float2*)&W2[k * 50 + m0];
                float2 wb = *(const float2*)&W2[k * 50 + m0 + 2];
                wv = make_float4(wa.x, wa.y, wb.x, wb.y);
            } else {
                float2 wa = *(const float2*)&W2[k * 50 + 48];
                wv = make_float4(wa.x, wa.y, 0.f, 0.f);
            }
            acc[0][0] = fmaf(xv.x, wv.x, acc[0][0]); acc[0][1] = fmaf(xv.x, wv.y, acc[0][1]);
            acc[0][2] = fmaf(xv.x, wv.z, acc[0][2]); acc[0][3] = fmaf(xv.x, wv.w, acc[0][3]);
            acc[1][0] = fmaf(xv.y, wv.x, acc[1][0]); acc[1][1] = fmaf(xv.y, wv.y, acc[1][1]);
            acc[1][2] = fmaf(xv.y, wv.z, acc[1][2]); acc[1][3] = fmaf(xv.y, wv.w, acc[1][3]);
            acc[2][0] = fmaf(xv.z, wv.x, acc[2][0]); acc[2][1] = fmaf(xv.z, wv.y, acc[2][1]);
            acc[2][2] = fmaf(xv.z, wv.z, acc[2][2]); acc[2][3] = fmaf(xv.z, wv.w, acc[2][3]);
            acc[3][0] = fmaf(xv.w, wv.x, acc[3][0]); acc[3][1] = fmaf(xv.w, wv.y, acc[3][1]);
            acc[3][2] = fmaf(xv.w, wv.z, acc[3][2]); acc[3][3] = fmaf(xv.w, wv.w, acc[3][3]);
        }
#pragma unroll
        for (int j = 0; j < 4; ++j) {
            int node = blockBase + n0 + j;
            if (node < n) {
                float dv = dinv[node];
                if (full) {
                    float4 r = make_float4(acc[j][0] * dv, acc[j][1] * dv,
                                           acc[j][2] * dv, acc[j][3] * dv);
                    *(float4*)&out[(size_t)node * 64 + m0] = r;
                } else {
                    out[(size_t)node * 64 + 48] = acc[j][0] * dv;
                    out[(size_t)node * 64 + 49] = acc[j][1] * dv;
                }
            }
        }
    }
}

// ---------------- fused layer-2/3: agg(M=50,relu+b2) + gemm(50->25,*dinv) ----------------
__global__ __launch_bounds__(256) void fused_l2(
    const float* __restrict__ s, const int* __restrict__ offs,
    const int* __restrict__ csr, const float* __restrict__ dinv,
    const float* __restrict__ b2, const float* __restrict__ W3,
    float* __restrict__ out, int n) {
    constexpr int NT = 32, NTp = 36;
    __shared__ float Xs[50 * NTp];   // 7.2 KB
    int blockBase = blockIdx.x * NT;
    int lane = threadIdx.x & 15;
    int f0 = lane * 4;
    bool active = f0 < 50;

#pragma unroll
    for (int pass = 0; pass < 2; ++pass) {
        int nl = pass * 16 + (threadIdx.x >> 4);
        int node = blockBase + nl;
        float4 r = make_float4(0.f, 0.f, 0.f, 0.f);
        if (node < n && active) {
            float4 z = make_float4(0.f, 0.f, 0.f, 0.f);
            float4 acc0 = *(const float4*)&s[(size_t)node * 64 + f0];
            float4 acc1 = z, acc2 = z, acc3 = z;
            int e0 = offs[node], e1 = offs[node + 1];
            int e = e0;
            for (; e + 4 <= e1; e += 4) {
                int i0 = csr[e], i1 = csr[e + 1], i2 = csr[e + 2], i3 = csr[e + 3];
                acc0 = add4(acc0, *(const float4*)&s[(size_t)i0 * 64 + f0]);
                acc1 = add4(acc1, *(const float4*)&s[(size_t)i1 * 64 + f0]);
                acc2 = add4(acc2, *(const float4*)&s[(size_t)i2 * 64 + f0]);
                acc3 = add4(acc3, *(const float4*)&s[(size_t)i3 * 64 + f0]);
            }
            for (; e < e1; ++e)
                acc0 = add4(acc0, *(const float4*)&s[(size_t)csr[e] * 64 + f0]);
            float4 acc = add4(add4(acc0, acc1), add4(acc2, acc3));
            float dv = dinv[node];
            r.x = fmaxf(dv * acc.x + b2[f0 + 0], 0.f);
            r.y = fmaxf(dv * acc.y + b2[f0 + 1], 0.f);
            if (f0 + 2 < 50) r.z = fmaxf(dv * acc.z + b2[f0 + 2], 0.f);
            if (f0 + 3 < 50) r.w = fmaxf(dv * acc.w + b2[f0 + 3], 0.f);
        }
        if (active) {
            Xs[(f0 + 0) * NTp + nl] = r.x;
            Xs[(f0 + 1) * NTp + nl] = r.y;
            if (f0 + 2 < 50) Xs[(f0 + 2) * NTp + nl] = r.z;
            if (f0 + 3 < 50) Xs[(f0 + 3) * NTp + nl] = r.w;
        }
    }
    __syncthreads();

    // phase B: K=50, M=25 (Mp=28, MQ=7), NTILES = 8*7 = 56
    if (threadIdx.x < 56) {
        int ng = threadIdx.x / 7, mq = threadIdx.x % 7;
        int n0 = ng * 4, m0 = mq * 4;
        float acc[4][4] = {};
#pragma unroll 2
        for (int k = 0; k < 50; ++k) {
            float4 xv = *(const float4*)&Xs[k * NTp + n0];
            float4 wv;
            wv.x = W3[k * 25 + m0];
            wv.y = (m0 + 1 < 25) ? W3[k * 25 + m0 + 1] : 0.f;
            wv.z = (m0 + 2 < 25) ? W3[k * 25 + m0 + 2] : 0.f;
            wv.w = (m0 + 3 < 25) ? W3[k * 25 + m0 + 3] : 0.f;
            acc[0][0] = fmaf(xv.x, wv.x, acc[0][0]); acc[0][1] = fmaf(xv.x, wv.y, acc[0][1]);
            acc[0][2] = fmaf(xv.x, wv.z, acc[0][2]); acc[0][3] = fmaf(xv.x, wv.w, acc[0][3]);
            acc[1][0] = fmaf(xv.y, wv.x, acc[1][0]); acc[1][1] = fmaf(xv.y, wv.y, acc[1][1]);
            acc[1][2] = fmaf(xv.y, wv.z, acc[1][2]); acc[1][3] = fmaf(xv.y, wv.w, acc[1][3]);
            acc[2][0] = fmaf(xv.z, wv.x, acc[2][0]); acc[2][1] = fmaf(xv.z, wv.y, acc[2][1]);
            acc[2][2] = fmaf(xv.z, wv.z, acc[2][2]); acc[2][3] = fmaf(xv.z, wv.w, acc[2][3]);
            acc[3][0] = fmaf(xv.w, wv.x, acc[3][0]); acc[3][1] = fmaf(xv.w, wv.y, acc[3][1]);
            acc[3][2] = fmaf(xv.w, wv.z, acc[3][2]); acc[3][3] = fmaf(xv.w, wv.w, acc[3][3]);
        }
#pragma unroll
        for (int j = 0; j < 4; ++j) {
            int node = blockBase + n0 + j;
            if (node < n) {
                float dv = dinv[node];
                if (m0 + 3 < 25) {
                    float4 r = make_float4(acc[j][0] * dv, acc[j][1] * dv,
                                           acc[j][2] * dv, acc[j][3] * dv);
                    *(float4*)&out[(size_t)node * 32 + m0] = r;
                } else {
                    out[(size_t)node * 32 + 24] = acc[j][0] * dv;
                }
            }
        }
    }
}

// ---------------- fused layer-3 aggregate + 3-layer MLP head (unchanged R7) ----------------
__global__ __launch_bounds__(256) void agg3_mlp(
    const float* __restrict__ s, const int* __restrict__ offs,
    const int* __restrict__ csr, const float* __restrict__ dinv,
    const float* __restrict__ bg,
    const float* __restrict__ Wl1, const float* __restrict__ bl1,
    const float* __restrict__ Wl2, const float* __restrict__ bl2,
    const float* __restrict__ Wl3, const float* __restrict__ bl3,
    float* __restrict__ out, int n) {
    constexpr int M = 25, S = 32, LPN = 8;
    __shared__ float W1s[625], W2s[250], W3s[10], b1s[25], b2s[10];
    __shared__ float accs[32 * 26];
    __shared__ float b3s;

    for (int i = threadIdx.x; i < 625; i += 256) W1s[i] = Wl1[i];
    for (int i = threadIdx.x; i < 250; i += 256) W2s[i] = Wl2[i];
    if (threadIdx.x < 10) { W3s[threadIdx.x] = Wl3[threadIdx.x]; b2s[threadIdx.x] = bl2[threadIdx.x]; }
    if (threadIdx.x < 25) b1s[threadIdx.x] = bl1[threadIdx.x];
    if (threadIdx.x == 0) b3s = bl3[0];

    int lane = threadIdx.x % LPN;
    int nl   = threadIdx.x / LPN;
    int node = blockIdx.x * 32 + nl;
    int f0 = lane * 4;

    if (node < n) {
        bool active = f0 < M;
        float dv = dinv[node];
        float4 z = make_float4(0.f, 0.f, 0.f, 0.f);
        float4 acc0 = z, acc1 = z, acc2 = z, acc3 = z;
        if (active) acc0 = *(const float4*)&s[(size_t)node * S + f0];

        int e0 = offs[node], e1 = offs[node + 1];
        int e = e0;
        for (; e + 4 <= e1; e += 4) {
            int i0 = csr[e], i1 = csr[e + 1], i2 = csr[e + 2], i3 = csr[e + 3];
            float4 v0 = z, v1 = z, v2 = z, v3 = z;
            if (active) {
                v0 = *(const float4*)&s[(size_t)i0 * S + f0];
                v1 = *(const float4*)&s[(size_t)i1 * S + f0];
                v2 = *(const float4*)&s[(size_t)i2 * S + f0];
                v3 = *(const float4*)&s[(size_t)i3 * S + f0];
            }
            acc0 = add4(acc0, v0); acc1 = add4(acc1, v1);
            acc2 = add4(acc2, v2); acc3 = add4(acc3, v3);
        }
        for (; e < e1; ++e) {
            int sid = csr[e];
            float4 v = active ? *(const float4*)&s[(size_t)sid * S + f0] : z;
            acc0 = add4(acc0, v);
        }
        float4 acc = add4(add4(acc0, acc1), add4(acc2, acc3));

        if (active) {
            float4 r = mul4s(acc, dv);
            if (f0 + 0 < M) accs[nl * 26 + f0 + 0] = fmaxf(r.x + bg[f0 + 0], 0.0f);
            if (f0 + 1 < M) accs[nl * 26 + f0 + 1] = fmaxf(r.y + bg[f0 + 1], 0.0f);
            if (f0 + 2 < M) accs[nl * 26 + f0 + 2] = fmaxf(r.z + bg[f0 + 2], 0.0f);
            if (f0 + 3 < M) accs[nl * 26 + f0 + 3] = fmaxf(r.w + bg[f0 + 3], 0.0f);
        }
    }
    __syncthreads();

    if (threadIdx.x < 32) {
        int nd = blockIdx.x * 32 + threadIdx.x;
        if (nd < n) {
            const float* xr = &accs[threadIdx.x * 26];
            float h1[25];
#pragma unroll
            for (int m = 0; m < 25; ++m) {
                float a = b1s[m];
#pragma unroll
                for (int k = 0; k < 25; ++k) a = fmaf(xr[k], W1s[k * 25 + m], a);
                h1[m] = fmaxf(a, 0.0f);
            }
            float h2[10];
#pragma unroll
            for (int m = 0; m < 10; ++m) {
                float a = b2s[m];
#pragma unroll
                for (int k = 0; k < 25; ++k) a = fmaf(h1[k], W2s[k * 10 + m], a);
                h2[m] = fmaxf(a, 0.0f);
            }
            float a = b3s;
#pragma unroll
            for (int k = 0; k < 10; ++k) a = fmaf(h2[k], W3s[k], a);
            out[nd] = fmaxf(a, 0.0f);
        }
    }
}

// ---------------- launch ----------------

extern "C" void kernel_launch(void* const* d_in, const int* in_sizes, int n_in,
                              void* d_out, int out_size, void* d_ws, size_t ws_size,
                              hipStream_t stream) {
    const float* x0  = (const float*)d_in[0];
    const float* W1  = (const float*)d_in[1];
    const float* b1  = (const float*)d_in[2];
    const float* W2  = (const float*)d_in[3];
    const float* b2  = (const float*)d_in[4];
    const float* W3  = (const float*)d_in[5];
    const float* b3  = (const float*)d_in[6];
    const float* Wl1 = (const float*)d_in[7];
    const float* bl1 = (const float*)d_in[8];
    const float* Wl2 = (const float*)d_in[9];
    const float* bl2 = (const float*)d_in[10];
    const float* Wl3 = (const float*)d_in[11];
    const float* bl3 = (const float*)d_in[12];
    const int*   edge = (const int*)d_in[13];

    int n  = in_sizes[0] / 64;      // 100000
    int ne = in_sizes[13] / 2;      // 1000000
    const int* esrc = edge;
    const int* edst = edge + ne;

    char* ws = (char*)d_ws;
    auto alloc = [&](size_t bytes) {
        char* p = ws;
        ws += (bytes + 255) & ~(size_t)255;
        return p;
    };
    int*   offs       = (int*)alloc((size_t)(n + 1) * 4);
    int*   bucketCur  = (int*)alloc(NBUCK * 4);
    int*   bucketBase = (int*)alloc(NBUCK * 4);
    int*   csr        = (int*)alloc((size_t)ne * 4);
    float* dinv       = (float*)alloc((size_t)n * 4);
    float* bufA       = (float*)alloc((size_t)n * 64 * 4);   // stride-64 (fused_l1 out)
    float* bufC       = (float*)alloc((size_t)n * 32 * 4);   // stride-32 (fused_l2 out)
    int*   pairs      = (int*)bufA;  // 256*6144*4 = 6.3MB, consumed before fused_l1 writes bufA
    (void)ws_size; (void)n_in; (void)out_size;

    int nbuckets = (n + (1 << BSHIFT) - 1) >> BSHIFT;   // 196
    int nblocks32 = (n + 31) / 32;

    // CSR + dinv (4 dispatches)
    zero_ints<<<1, 256, 0, stream>>>(bucketCur, NBUCK);
    partition_edges<<<(ne + 256 * EPT - 1) / (256 * EPT), 256, 0, stream>>>(
        esrc, edst, bucketCur, pairs, ne);
    scan_buckets<<<1, 256, 0, stream>>>(bucketCur, bucketBase, offs, n, ne, nbuckets);
    bucket_csr<<<nbuckets, 256, 0, stream>>>(pairs, bucketCur, bucketBase, offs, dinv, csr, n);

    // GCN layer 1+2 head: bufA = (relu(ÂX@W1+b1) @ W2) * dinv  (stride 64, cols 0..49)
    fused_l1<<<nblocks32, 256, 0, stream>>>(x0, offs, csr, dinv, W1, b1, W2, bufA, n);

    // GCN layer 2 aggregate + layer-3 transform: bufC = (relu(dinv*agg(bufA)+b2) @ W3)*dinv
    fused_l2<<<nblocks32, 256, 0, stream>>>(bufA, offs, csr, dinv, b2, W3, bufC, n);

    // GCN layer 3 aggregate + MLP head -> d_out
    agg3_mlp<<<nblocks32, 256, 0, stream>>>(
        bufC, offs, csr, dinv, b3, Wl1, bl1, Wl2, bl2, Wl3, bl3, (float*)d_out, n);
}